// Round 16
// baseline (103.302 us; speedup 1.0000x reference)
//
#include <hip/hip_runtime.h>
#include <hip/hip_bf16.h>
#include <stdint.h>

#define NROWS 8192
#define NDIM  512
#define MARGIN 0.3f
#define NT    2080     // 64*65/2 upper-triangular 128x128 blocks

typedef __attribute__((ext_vector_type(16))) float floatx16;
typedef __attribute__((ext_vector_type(8)))  int   intx8;

// pack 4 floats -> 4 OCP e4m3 bytes (HW cvt, RNE, saturating)
__device__ inline unsigned cvt4_fp8(float4 f) {
  int v = 0;
  v = __builtin_amdgcn_cvt_pk_fp8_f32(f.x, f.y, v, false);
  v = __builtin_amdgcn_cvt_pk_fp8_f32(f.z, f.w, v, true);
  return (unsigned)v;
}

// fp32 -> fp8 e4m3, 16 floats/thread
__global__ void convert_kernel(const float4* __restrict__ in, uint4* __restrict__ out) {
  int i = blockIdx.x * blockDim.x + threadIdx.x;
  float4 f0 = in[i * 4 + 0], f1 = in[i * 4 + 1], f2 = in[i * 4 + 2], f3 = in[i * 4 + 3];
  uint4 o;
  o.x = cvt4_fp8(f0);
  o.y = cvt4_fp8(f1);
  o.z = cvt4_fp8(f2);
  o.w = cvt4_fp8(f3);
  out[i] = o;
}

__device__ inline void gload_lds16(const void* g, void* l) {
  __builtin_amdgcn_global_load_lds(
      (const __attribute__((address_space(1))) unsigned int*)g,
      (__attribute__((address_space(3))) unsigned int*)l, 16, 0, 0);
}

// 128x128 upper-tri blocks of sim = X·X^T, fp8 e4m3 via MX-scaled
// v_mfma_scale_f32_32x32x64_f8f6f4 (scale=1.0; R10/R14-verified correct).
// R16 = R14 core on a REGISTER DIET to reach 4 waves/SIMD without spilling
// (R11 spilled at ~134 regs; here: acc 64 + frag 32 + ~12 addr/misc ≈ 110):
//  - staging: ONE offset VGPR; chunk-pair (+16 rows) and B-matrix are uniform
//    base-pointer deltas (SGPR), since (row>>2)&3 is invariant under +16.
//  - ds_read: FOUR base VGPRs (A-lo/A-hi/B-lo/B-hi); mt stride +2048 and
//    buf stride +8192 are compile-time immediates (loop fully unrolled).
//  - fragments assembled by writing the two int4 loads straight into the
//    intx8 halves (no per-element repack).
// 2-stage 32 KB LDS -> 4 blocks/CU at 4 waves/SIMD = 16 waves/CU.
// Ordering per iter (R14-verified): own vmcnt(0) on loads issued one full
// compute-phase ago -> raw s_barrier (no lgkm drain) -> stage kt+1 -> compute.
__launch_bounds__(256, 4)
__global__ void loss_kernel(const unsigned char* __restrict__ Xb, const int* __restrict__ tg,
                            float* __restrict__ partials) {
  __shared__ __align__(16) unsigned char As[2][8192];   // 128 rows x 64 B
  __shared__ __align__(16) unsigned char Bs[2][8192];
  __shared__ float red[4];

  // super-tile decode (8 diagonal supers of 36, then 28 off-diag of 64)
  int t = blockIdx.x;
  int bi, bj;
  if (t < 288) {
    int si = t / 36;
    int q  = t - si * 36;
    int ii = 0;
    while (q >= 8 - ii) { q -= 8 - ii; ii++; }
    bi = si * 8 + ii;
    bj = si * 8 + ii + q;
  } else {
    int q = t - 288;
    int s = q >> 6, r = q & 63;
    int si = 0;
    while (s >= 7 - si) { s -= 7 - si; si++; }
    int sj = si + 1 + s;
    bi = si * 8 + (r >> 3);
    bj = sj * 8 + (r & 7);
  }

  const int tid  = threadIdx.x;
  const int lane = tid & 63;
  const int w    = tid >> 6;
  const int wm   = w >> 1, wn = w & 1;   // 2x2 waves, 64x64 each
  const int g    = lane >> 5;            // MFMA k-group (0/1)
  const int m32  = lane & 31;            // MFMA row/col within 32

  const int rowBase = bi * 128;
  const int colBase = bj * 128;

  // uniform base pointers (SGPR): A, A+16rows, B, B+16rows
  const unsigned char* XA  = Xb + (size_t)rowBase * NDIM;
  const unsigned char* XA1 = XA + 16 * NDIM;
  const unsigned char* XB  = Xb + (size_t)colBase * NDIM;
  const unsigned char* XB1 = XB + 16 * NDIM;

  // staging: tile = 128 rows x 64 B = 8 chunks of 1 KB (16 rows each);
  // wave w stages chunks {2w, 2w+1} of A and of B. Chunk lane d:
  // row = ch*16 + (d>>2), u_phys = d&3, fetches u_log = u_phys ^ ((row>>2)&3).
  // (row>>2)&3 is invariant under row+16, so chunk 2w+1 = same offset off XA1.
  const int srow0 = (w * 2) * 16 + (lane >> 2);            // row for chunk 2w
  const unsigned gOff = (unsigned)(srow0 * NDIM +
                        ((lane & 3) ^ ((srow0 >> 2) & 3)) * 16);

#define STAGE(KT, BUF)                                                     \
  do {                                                                     \
    gload_lds16(XA  + gOff + (KT) * 64, &As[BUF][(w * 2)     * 1024]);     \
    gload_lds16(XA1 + gOff + (KT) * 64, &As[BUF][(w * 2 + 1) * 1024]);     \
    gload_lds16(XB  + gOff + (KT) * 64, &Bs[BUF][(w * 2)     * 1024]);     \
    gload_lds16(XB1 + gOff + (KT) * 64, &Bs[BUF][(w * 2 + 1) * 1024]);     \
  } while (0)

  // ds_read bases (byte offsets into a tile). mt/nt=1 adds +2048 (imm),
  // buf adds +8192 (imm). hi = the (2g+1)^x unit (lane-dependent vs lo).
  const int rowA = wm * 64 + m32;                 // mt=0 fragment row
  const int xA   = (rowA >> 2) & 3;
  const int aLo  = rowA * 64 + (((2 * g)     ^ xA) << 4);
  const int aHi  = rowA * 64 + (((2 * g + 1) ^ xA) << 4);
  const int rowB = wn * 64 + m32;
  const int xB   = (rowB >> 2) & 3;
  const int bLo  = rowB * 64 + (((2 * g)     ^ xB) << 4);
  const int bHi  = rowB * 64 + (((2 * g + 1) ^ xB) << 4);

  floatx16 acc[2][2];
#pragma unroll
  for (int a = 0; a < 2; a++)
#pragma unroll
    for (int b = 0; b < 2; b++) acc[a][b] = (floatx16)(0.f);

  STAGE(0, 0);

#pragma unroll
  for (int kt = 0; kt < 8; kt++) {
    const int buf = kt & 1;
    // own stage-kt DMA drained (issued one compute-phase ago); barrier =>
    // ALL waves' stage-kt landed AND all kt-1 reads consumed (WAR-safe).
    asm volatile("s_waitcnt vmcnt(0)" ::: "memory");
    asm volatile("s_barrier" ::: "memory");          // raw: no lgkm drain
    if (kt < 7) STAGE(kt + 1, buf ^ 1);              // flies under kt compute

    intx8 af[2], bf[2];
#pragma unroll
    for (int mt = 0; mt < 2; mt++) {
      ((int4*)&af[mt])[0] = *(const int4*)(&As[buf][aLo + mt * 2048]);
      ((int4*)&af[mt])[1] = *(const int4*)(&As[buf][aHi + mt * 2048]);
    }
#pragma unroll
    for (int nt = 0; nt < 2; nt++) {
      ((int4*)&bf[nt])[0] = *(const int4*)(&Bs[buf][bLo + nt * 2048]);
      ((int4*)&bf[nt])[1] = *(const int4*)(&Bs[buf][bHi + nt * 2048]);
    }
#pragma unroll
    for (int mt = 0; mt < 2; mt++)
#pragma unroll
      for (int nt = 0; nt < 2; nt++)
        acc[mt][nt] = __builtin_amdgcn_mfma_scale_f32_32x32x64_f8f6f4(
            af[mt], bf[nt], acc[mt][nt],
            0 /*A fmt: fp8 e4m3*/, 0 /*B fmt: fp8 e4m3*/,
            0, 127 /*scaleA = 2^0*/, 0, 127 /*scaleB = 2^0*/);
  }

  // Epilogue (R10/R14-verified). 32x32 C/D layout [m74/m101]: col = lane&31,
  // row = (reg&3) + 8*(reg>>2) + 4*(lane>>5), reg in [0,16).
  float lsum = 0.f;
  const bool diag = (bi == bj);
  if (!diag) {
#pragma unroll
    for (int mt = 0; mt < 2; mt++) {
#pragma unroll
      for (int nt = 0; nt < 2; nt++) {
        const int tc = tg[colBase + wn * 64 + nt * 32 + m32];
#pragma unroll
        for (int q = 0; q < 4; q++) {
          const int4 rlv = *(const int4*)(tg + rowBase + wm * 64 + mt * 32 + 4 * g + 8 * q);
          const int rlab[4] = {rlv.x, rlv.y, rlv.z, rlv.w};
#pragma unroll
          for (int j = 0; j < 4; j++) {
            const float s = acc[mt][nt][q * 4 + j];
            lsum += (rlab[j] == tc) ? ((s < 1.f) ? 1.f - s : 0.f)
                                    : ((s > MARGIN) ? s : 0.f);
          }
        }
      }
    }
    lsum *= 2.f;     // pair weight hoisted
  } else {
#pragma unroll
    for (int mt = 0; mt < 2; mt++) {
#pragma unroll
      for (int nt = 0; nt < 2; nt++) {
        const int cloc = wn * 64 + nt * 32 + m32;
        const int tc = tg[colBase + cloc];
        const int col = colBase + cloc;
#pragma unroll
        for (int q = 0; q < 4; q++) {
          const int rbase = wm * 64 + mt * 32 + 4 * g + 8 * q;
          const int4 rlv = *(const int4*)(tg + rowBase + rbase);
          const int rlab[4] = {rlv.x, rlv.y, rlv.z, rlv.w};
#pragma unroll
          for (int j = 0; j < 4; j++) {
            const float s = acc[mt][nt][q * 4 + j];
            float c = (rlab[j] == tc) ? ((s < 1.f) ? 1.f - s : 0.f)
                                      : ((s > MARGIN) ? s : 0.f);
            const int row = rowBase + rbase + j;
            float wgt = (row < col) ? 2.f : ((row == col) ? 1.f : 0.f);
            lsum += wgt * c;
          }
        }
      }
    }
  }

  // block reduce, ONE non-atomic partial store per block
#pragma unroll
  for (int off = 32; off > 0; off >>= 1) lsum += __shfl_down(lsum, off, 64);
  if (lane == 0) red[w] = lsum;
  __syncthreads();
  if (tid == 0) partials[blockIdx.x] = red[0] + red[1] + red[2] + red[3];
}

// 2080 partials -> scalar; one 256-thread block
__global__ void reduce_kernel(const float* __restrict__ partials, float* __restrict__ out) {
  __shared__ float red[4];
  float s = 0.f;
  for (int i = threadIdx.x; i < NT; i += 256) s += partials[i];
#pragma unroll
  for (int off = 32; off > 0; off >>= 1) s += __shfl_down(s, off, 64);
  if ((threadIdx.x & 63) == 0) red[threadIdx.x >> 6] = s;
  __syncthreads();
  if (threadIdx.x == 0)
    out[0] = (red[0] + red[1] + red[2] + red[3]) * (1.0f / NROWS);
}

extern "C" void kernel_launch(void* const* d_in, const int* in_sizes, int n_in,
                              void* d_out, int out_size, void* d_ws, size_t ws_size,
                              hipStream_t stream) {
  const float* x = (const float*)d_in[0];
  const int* tg  = (const int*)d_in[1];
  float* out     = (float*)d_out;
  unsigned char* xb = (unsigned char*)d_ws;                    // fp8 X, 4 MiB
  float* partials   = (float*)((char*)d_ws + (4u << 20));      // 2080 floats

  convert_kernel<<<(NROWS * NDIM / 16) / 256, 256, 0, stream>>>(
      (const float4*)x, (uint4*)xb);
  loss_kernel<<<NT, 256, 0, stream>>>(xb, tg, partials);
  reduce_kernel<<<1, 256, 0, stream>>>(partials, out);
}

// Round 17
// 100.836 us; speedup vs baseline: 1.0245x; 1.0245x over previous
//
#include <hip/hip_runtime.h>
#include <hip/hip_bf16.h>
#include <stdint.h>

#define NROWS 8192
#define NDIM  512
#define MARGIN 0.3f
#define NT    2080     // 64*65/2 upper-triangular 128x128 blocks

typedef __attribute__((ext_vector_type(16))) float floatx16;
typedef __attribute__((ext_vector_type(8)))  int   intx8;

// pack 4 floats -> 4 OCP e4m3 bytes (HW cvt, RNE, saturating)
__device__ inline unsigned cvt4_fp8(float4 f) {
  int v = 0;
  v = __builtin_amdgcn_cvt_pk_fp8_f32(f.x, f.y, v, false);
  v = __builtin_amdgcn_cvt_pk_fp8_f32(f.z, f.w, v, true);
  return (unsigned)v;
}

// fp32 -> fp8 e4m3, 16 floats/thread
__global__ void convert_kernel(const float4* __restrict__ in, uint4* __restrict__ out) {
  int i = blockIdx.x * blockDim.x + threadIdx.x;
  float4 f0 = in[i * 4 + 0], f1 = in[i * 4 + 1], f2 = in[i * 4 + 2], f3 = in[i * 4 + 3];
  uint4 o;
  o.x = cvt4_fp8(f0);
  o.y = cvt4_fp8(f1);
  o.z = cvt4_fp8(f2);
  o.w = cvt4_fp8(f3);
  out[i] = o;
}

__device__ inline void gload_lds16(const void* g, void* l) {
  __builtin_amdgcn_global_load_lds(
      (const __attribute__((address_space(1))) unsigned int*)g,
      (__attribute__((address_space(3))) unsigned int*)l, 16, 0, 0);
}

// 128x128 upper-tri blocks of sim = X·X^T, fp8 e4m3 via MX-scaled
// v_mfma_scale_f32_32x32x64_f8f6f4 (scale=1.0; R10/R14-verified correct).
// R17 = R15 (best, 99.4) with ONE change: STAGE(kt+2) is issued AFTER the
// fragment ds_reads instead of before. Rationale: DMA LDS-writes and the
// waves' ds_reads share the LDS port; issuing 16 KB of DMA first at
// barrier-exit delays the reads the MFMAs wait on. Distance-2 gives the
// prefetch ~900 cyc of slack, so delaying its ISSUE by the read phase is
// free, while reads (and thus MFMAs) start immediately at barrier-exit.
// Everything else identical to R15: 3-stage BK=64 (48 KB -> 3 blocks/CU),
// per-wave s_waitcnt vmcnt(4) mid-loop (never 0 until last iter), raw
// s_barrier (no lgkm drain), block partial -> d_ws, separate reduce.
__launch_bounds__(256, 3)
__global__ void loss_kernel(const unsigned char* __restrict__ Xb, const int* __restrict__ tg,
                            float* __restrict__ partials) {
  __shared__ __align__(16) unsigned char As[3][8192];   // 128 rows x 64 B
  __shared__ __align__(16) unsigned char Bs[3][8192];
  __shared__ float red[4];

  // super-tile decode (8 diagonal supers of 36, then 28 off-diag of 64)
  int t = blockIdx.x;
  int bi, bj;
  if (t < 288) {
    int si = t / 36;
    int q  = t - si * 36;
    int ii = 0;
    while (q >= 8 - ii) { q -= 8 - ii; ii++; }
    bi = si * 8 + ii;
    bj = si * 8 + ii + q;
  } else {
    int q = t - 288;
    int s = q >> 6, r = q & 63;
    int si = 0;
    while (s >= 7 - si) { s -= 7 - si; si++; }
    int sj = si + 1 + s;
    bi = si * 8 + (r >> 3);
    bj = sj * 8 + (r & 7);
  }

  const int tid  = threadIdx.x;
  const int lane = tid & 63;
  const int w    = tid >> 6;
  const int wm   = w >> 1, wn = w & 1;   // 2x2 waves, 64x64 each
  const int g    = lane >> 5;            // MFMA k-group (0/1)
  const int m32  = lane & 31;            // MFMA row/col within 32

  const int rowBase = bi * 128;
  const int colBase = bj * 128;

  // staging: tile = 128 rows x 64 B = 8 chunks of 1 KB (16 rows each);
  // wave w stages chunks {2w, 2w+1} of A and of B (4 DMA loads/wave/stage).
  // Chunk lane d: row = ch*16 + (d>>2), u_phys = d&3; fetches global k-unit
  // u_log = u_phys ^ ((row>>2)&3)  (conflict-free b128 reads, R14-verified).
  const int srow = lane >> 2;
  const int sup  = lane & 3;
  unsigned gA[2], gB[2];
#pragma unroll
  for (int c = 0; c < 2; c++) {
    int ch  = w * 2 + c;
    int row = ch * 16 + srow;
    int ul  = sup ^ ((row >> 2) & 3);
    gA[c] = (unsigned)((rowBase + row) * NDIM + ul * 16);
    gB[c] = (unsigned)((colBase + row) * NDIM + ul * 16);
  }

#define STAGE(KT, BUF)                                                    \
  do {                                                                    \
    _Pragma("unroll")                                                     \
    for (int c = 0; c < 2; c++) {                                         \
      int ch = w * 2 + c;                                                 \
      gload_lds16(Xb + gA[c] + (KT) * 64, &As[BUF][ch * 1024]);           \
      gload_lds16(Xb + gB[c] + (KT) * 64, &Bs[BUF][ch * 1024]);           \
    }                                                                     \
  } while (0)

  floatx16 acc[2][2];
#pragma unroll
  for (int a = 0; a < 2; a++)
#pragma unroll
    for (int b = 0; b < 2; b++) acc[a][b] = (floatx16)(0.f);

  STAGE(0, 0);
  STAGE(1, 1);

#pragma unroll
  for (int kt = 0; kt < 8; kt++) {
    const int buf = kt % 3;
    // tile kt landed (own 4 oldest loads retired); kt+1's 4 stay in flight.
    if (kt < 7) asm volatile("s_waitcnt vmcnt(4)" ::: "memory");
    else        asm volatile("s_waitcnt vmcnt(0)" ::: "memory");
    asm volatile("s_barrier" ::: "memory");        // raw: no lgkm drain

    // fragment reads FIRST (LDS port serves them at barrier-exit, MFMAs
    // unblock ASAP); prefetch DMA is issued after (has ~1 iter of slack)
    intx8 af[2], bf[2];
#pragma unroll
    for (int mt = 0; mt < 2; mt++) {
      const int row = wm * 64 + mt * 32 + m32;
      const int x = (row >> 2) & 3;
      int4 lo = *(const int4*)(&As[buf][row * 64 + ((2 * g)     ^ x) * 16]);
      int4 hi = *(const int4*)(&As[buf][row * 64 + ((2 * g + 1) ^ x) * 16]);
      intx8 f; f[0]=lo.x; f[1]=lo.y; f[2]=lo.z; f[3]=lo.w;
               f[4]=hi.x; f[5]=hi.y; f[6]=hi.z; f[7]=hi.w;
      af[mt] = f;
    }
#pragma unroll
    for (int nt = 0; nt < 2; nt++) {
      const int row = wn * 64 + nt * 32 + m32;
      const int x = (row >> 2) & 3;
      int4 lo = *(const int4*)(&Bs[buf][row * 64 + ((2 * g)     ^ x) * 16]);
      int4 hi = *(const int4*)(&Bs[buf][row * 64 + ((2 * g + 1) ^ x) * 16]);
      intx8 f; f[0]=lo.x; f[1]=lo.y; f[2]=lo.z; f[3]=lo.w;
               f[4]=hi.x; f[5]=hi.y; f[6]=hi.z; f[7]=hi.w;
      bf[nt] = f;
    }

    if (kt < 6) STAGE(kt + 2, (kt + 2) % 3);       // distance-2 prefetch

#pragma unroll
    for (int mt = 0; mt < 2; mt++)
#pragma unroll
      for (int nt = 0; nt < 2; nt++)
        acc[mt][nt] = __builtin_amdgcn_mfma_scale_f32_32x32x64_f8f6f4(
            af[mt], bf[nt], acc[mt][nt],
            0 /*A fmt: fp8 e4m3*/, 0 /*B fmt: fp8 e4m3*/,
            0, 127 /*scaleA = 2^0*/, 0, 127 /*scaleB = 2^0*/);
  }

  // Epilogue (R10/R14-verified). 32x32 C/D layout [m74/m101]: col = lane&31,
  // row = (reg&3) + 8*(reg>>2) + 4*(lane>>5), reg in [0,16).
  float lsum = 0.f;
  const bool diag = (bi == bj);
  if (!diag) {
#pragma unroll
    for (int mt = 0; mt < 2; mt++) {
#pragma unroll
      for (int nt = 0; nt < 2; nt++) {
        const int tc = tg[colBase + wn * 64 + nt * 32 + m32];
#pragma unroll
        for (int q = 0; q < 4; q++) {
          const int4 rlv = *(const int4*)(tg + rowBase + wm * 64 + mt * 32 + 4 * g + 8 * q);
          const int rlab[4] = {rlv.x, rlv.y, rlv.z, rlv.w};
#pragma unroll
          for (int j = 0; j < 4; j++) {
            const float s = acc[mt][nt][q * 4 + j];
            lsum += (rlab[j] == tc) ? ((s < 1.f) ? 1.f - s : 0.f)
                                    : ((s > MARGIN) ? s : 0.f);
          }
        }
      }
    }
    lsum *= 2.f;     // pair weight hoisted
  } else {
#pragma unroll
    for (int mt = 0; mt < 2; mt++) {
#pragma unroll
      for (int nt = 0; nt < 2; nt++) {
        const int cloc = wn * 64 + nt * 32 + m32;
        const int tc = tg[colBase + cloc];
        const int col = colBase + cloc;
#pragma unroll
        for (int q = 0; q < 4; q++) {
          const int rbase = wm * 64 + mt * 32 + 4 * g + 8 * q;
          const int4 rlv = *(const int4*)(tg + rowBase + rbase);
          const int rlab[4] = {rlv.x, rlv.y, rlv.z, rlv.w};
#pragma unroll
          for (int j = 0; j < 4; j++) {
            const float s = acc[mt][nt][q * 4 + j];
            float c = (rlab[j] == tc) ? ((s < 1.f) ? 1.f - s : 0.f)
                                      : ((s > MARGIN) ? s : 0.f);
            const int row = rowBase + rbase + j;
            float wgt = (row < col) ? 2.f : ((row == col) ? 1.f : 0.f);
            lsum += wgt * c;
          }
        }
      }
    }
  }

  // block reduce, ONE non-atomic partial store per block
#pragma unroll
  for (int off = 32; off > 0; off >>= 1) lsum += __shfl_down(lsum, off, 64);
  if (lane == 0) red[w] = lsum;
  __syncthreads();
  if (tid == 0) partials[blockIdx.x] = red[0] + red[1] + red[2] + red[3];
}

// 2080 partials -> scalar; one 256-thread block
__global__ void reduce_kernel(const float* __restrict__ partials, float* __restrict__ out) {
  __shared__ float red[4];
  float s = 0.f;
  for (int i = threadIdx.x; i < NT; i += 256) s += partials[i];
#pragma unroll
  for (int off = 32; off > 0; off >>= 1) s += __shfl_down(s, off, 64);
  if ((threadIdx.x & 63) == 0) red[threadIdx.x >> 6] = s;
  __syncthreads();
  if (threadIdx.x == 0)
    out[0] = (red[0] + red[1] + red[2] + red[3]) * (1.0f / NROWS);
}

extern "C" void kernel_launch(void* const* d_in, const int* in_sizes, int n_in,
                              void* d_out, int out_size, void* d_ws, size_t ws_size,
                              hipStream_t stream) {
  const float* x = (const float*)d_in[0];
  const int* tg  = (const int*)d_in[1];
  float* out     = (float*)d_out;
  unsigned char* xb = (unsigned char*)d_ws;                    // fp8 X, 4 MiB
  float* partials   = (float*)((char*)d_ws + (4u << 20));      // 2080 floats

  convert_kernel<<<(NROWS * NDIM / 16) / 256, 256, 0, stream>>>(
      (const float4*)x, (uint4*)xb);
  loss_kernel<<<NT, 256, 0, stream>>>(xb, tg, partials);
  reduce_kernel<<<1, 256, 0, stream>>>(partials, out);
}